// Round 1
// baseline (579.026 us; speedup 1.0000x reference)
//
#include <hip/hip_runtime.h>
#include <hip/hip_bf16.h>
#include <stdint.h>

#define N_NODES 50000
#define N_EDGES 800000
#define K_KEEP  40000
#define BKT     196        // ceil(N_NODES/256) dst-range buckets
#define BCAP    6144       // per-bucket capacity (mean 4081, +32 sigma)

typedef unsigned long long u64;
typedef unsigned int u32;
typedef unsigned short u16;
typedef __hip_bfloat16 bf16;
typedef __hip_bfloat162 bf16x2;
typedef __attribute__((ext_vector_type(8))) short short8;
typedef __attribute__((ext_vector_type(4))) float f32x4;

struct Ctl {
  u64 prefix;
  u32 kremain;
  u32 cnt;
  float inv_norm;
  u32 isfp32;
  u32 done;
  u32 pad;          // csr2 edge cursor
  u32 hist[256];    // unused (layout keep)
};

__device__ __forceinline__ float bf2f(bf16 v) { return __bfloat162float(v); }
__device__ __forceinline__ float loadF(const void* p, size_t i, bool f32) {
  return f32 ? ((const float*)p)[i] : bf2f(((const bf16*)p)[i]);
}
__device__ __forceinline__ short f2bf_bits(float f) {
  bf16 t = __float2bfloat16(f);
  return *(const short*)&t;
}

// ---------------- init (+parallel dtype detect, proven R5-R8) ----------------

__global__ void init_kernel(const unsigned short* __restrict__ x16,
                            int* __restrict__ bucket_cur, int* __restrict__ detcnt,
                            Ctl* ctl, u32* __restrict__ hist16) {
  __shared__ u32 dsh[256];
  int i = blockIdx.x * 256 + threadIdx.x;
  if (i < BKT) bucket_cur[i] = i * BCAP;
  for (int j = i; j < 65536 + 256; j += gridDim.x * 256) hist16[j] = 0u;  // hist16 + coarse
  if (blockIdx.x == 0 && threadIdx.x == 0) {
    ctl->prefix = 0ull; ctl->kremain = K_KEEP; ctl->cnt = 0u; ctl->done = 0u; ctl->pad = 0u;
  }
  if (blockIdx.x < 64) {
    int base = blockIdx.x * 2048;
    u32 c = 0;
    for (int j = threadIdx.x; j < 2048; j += 256) {
      u32 h = x16[base + j];
      if ((h & 0x7F80u) == 0x7F80u) c++;
    }
    dsh[threadIdx.x] = c;
    __syncthreads();
    for (int s = 128; s > 0; s >>= 1) {
      if (threadIdx.x < s) dsh[threadIdx.x] += dsh[threadIdx.x + s];
      __syncthreads();
    }
    if (threadIdx.x == 0) detcnt[blockIdx.x] = (int)dsh[0];
  }
}

__global__ void norm_kernel(const void* __restrict__ pw, const int* __restrict__ detcnt, Ctl* ctl) {
  int lane = threadIdx.x;   // 64
  int dc = detcnt[lane];
  for (int off = 32; off; off >>= 1) dc += __shfl_down(dc, off);
  dc = __shfl(dc, 0);
  bool f32 = (dc >= 16);
  float v0 = loadF(pw, lane, f32);
  float v1 = loadF(pw, 64 + lane, f32);
  float s = v0 * v0 + v1 * v1;
  for (int off = 32; off; off >>= 1) s += __shfl_down(s, off);
  if (lane == 0) {
    ctl->inv_norm = 1.0f / sqrtf(s);
    ctl->isfp32 = f32 ? 1u : 0u;
  }
}

// ------------- CSR1 via bucket sort (proven R8) + fused x->bf16 convert -------------

__global__ void bucket_scatter_kernel(const int* __restrict__ src, const int* __restrict__ dst,
                                      int* __restrict__ bucket_cur, u32* __restrict__ bucketbuf,
                                      const void* __restrict__ x, u32* __restrict__ xbf,
                                      const Ctl* __restrict__ ctl)
{
  __shared__ u32 hist[BKT];
  __shared__ u32 base[BKT];
  const int tid = threadIdx.x;
  const int e0 = blockIdx.x * 2048;
  for (int t = tid; t < BKT; t += 256) hist[t] = 0;
  __syncthreads();
  #pragma unroll
  for (int j = 0; j < 8; ++j) {
    int e = e0 + j * 256 + tid;
    if (e < N_EDGES) atomicAdd(&hist[dst[e] >> 8], 1u);
  }
  __syncthreads();
  for (int t = tid; t < BKT; t += 256) {
    u32 c = hist[t];
    base[t] = c ? (u32)atomicAdd(&bucket_cur[t], (int)c) : 0u;
    hist[t] = 0;
  }
  __syncthreads();
  #pragma unroll
  for (int j = 0; j < 8; ++j) {
    int e = e0 + j * 256 + tid;
    if (e < N_EDGES) {
      int d = dst[e];
      int b = d >> 8;
      u32 pos = base[b] + atomicAdd(&hist[b], 1u);
      bucketbuf[pos] = ((u32)src[e] << 8) | (u32)(d & 255);
    }
  }
  // fused x -> bf16 (pair) conversion; 391 blocks * 4096 pairs >= 1,600,000
  {
    const bool f32 = ctl->isfp32 != 0;
    const int p0 = blockIdx.x * 4096;
    if (f32) {
      const float2* xf = (const float2*)x;
      for (int j = tid; j < 4096; j += 256) {
        int p = p0 + j;
        if (p < N_NODES * 32) {
          float2 v = xf[p];
          u32 w = ((u32)(u16)f2bf_bits(v.y) << 16) | (u32)(u16)f2bf_bits(v.x);
          xbf[p] = w;
        }
      }
    } else {
      const u32* xi = (const u32*)x;
      for (int j = tid; j < 4096; j += 256) {
        int p = p0 + j;
        if (p < N_NODES * 32) xbf[p] = xi[p];
      }
    }
  }
}

__global__ void scan_buckets_kernel(const int* __restrict__ bucket_cur, int* __restrict__ boff,
                                    int* __restrict__ rowstart_n)
{
  __shared__ int sh[256];
  int tid = threadIdx.x;
  int v = (tid < BKT) ? (bucket_cur[tid] - tid * BCAP) : 0;
  sh[tid] = v;
  __syncthreads();
  for (int off = 1; off < 256; off <<= 1) {
    int t = (tid >= off) ? sh[tid - off] : 0;
    __syncthreads();
    sh[tid] += t;
    __syncthreads();
  }
  if (tid < BKT) boff[tid] = sh[tid] - v;
  if (tid == 255) *rowstart_n = sh[255];
}

__global__ void csr_from_buckets_kernel(const u32* __restrict__ bucketbuf, const int* __restrict__ bucket_cur,
                                        const int* __restrict__ boff, int* __restrict__ rowstart,
                                        float* __restrict__ dis, int* __restrict__ csr)
{
  __shared__ u32 cnt[256];
  __shared__ u32 loc[256];
  __shared__ u32 cur[256];
  const int b = blockIdx.x;
  const int tid = threadIdx.x;
  const int bc = bucket_cur[b] - b * BCAP;
  const u32* buf = bucketbuf + (size_t)b * BCAP;
  const int off0 = boff[b];
  cnt[tid] = 0;
  __syncthreads();
  for (int i = tid; i < bc; i += 256) atomicAdd(&cnt[buf[i] & 255u], 1u);
  __syncthreads();
  u32 c = cnt[tid];
  loc[tid] = c;
  __syncthreads();
  for (int off = 1; off < 256; off <<= 1) {
    u32 t = (tid >= off) ? loc[tid - off] : 0;
    __syncthreads();
    loc[tid] += t;
    __syncthreads();
  }
  int node = b * 256 + tid;
  u32 excl = loc[tid] - c;
  if (node < N_NODES) {
    rowstart[node] = off0 + (int)excl;
    dis[node] = rsqrtf(1.0f + (float)c);
  }
  cur[tid] = off0 + excl;
  __syncthreads();
  for (int i = tid; i < bc; i += 256) {
    u32 p = buf[i];
    u32 pos = atomicAdd(&cur[p & 255u], 1u);
    csr[pos] = (int)(p >> 8);
  }
}

// ---------------- 16-bit radix pick (two-level: coarse 256 + fine 64K) ----------------

__device__ void pick16_dev(Ctl* ctl, u32* hist16, u32* coarse, int shift) {
  __shared__ u32 psh[256];
  __shared__ int pcb;
  __shared__ u32 pabove;
  const int tid = threadIdx.x;
  u32 c = atomicExch(&coarse[tid], 0u);      // coherent read + zero for next pass
  psh[tid] = c;
  __syncthreads();
  // inclusive suffix scan
  for (int off = 1; off < 256; off <<= 1) {
    u32 t = (tid + off < 256) ? psh[tid + off] : 0u;
    __syncthreads();
    psh[tid] += t;
    __syncthreads();
  }
  u32 kr = ctl->kremain;
  u32 E = (tid < 255) ? psh[tid + 1] : 0u;   // strict-above count
  if (E < kr && E + c >= kr) { pcb = tid; pabove = E; }
  __syncthreads();
  int cb = pcb;
  u32 above = pabove;
  u32 f = atomicAdd(&hist16[cb * 256 + tid], 0u);  // coherent read
  psh[tid] = f;
  __syncthreads();
  for (int off = 1; off < 256; off <<= 1) {
    u32 t = (tid + off < 256) ? psh[tid + off] : 0u;
    __syncthreads();
    psh[tid] += t;
    __syncthreads();
  }
  u32 Ef = above + ((tid < 255) ? psh[tid + 1] : 0u);
  if (Ef < kr && Ef + f >= kr) {
    ctl->prefix = ctl->prefix | (((u64)(u32)(cb * 256 + tid)) << shift);
    ctl->kremain = kr - Ef;
    ctl->done = 0u;
  }
  __syncthreads();
  if (shift > 0)
    for (int j = tid; j < 65536; j += 256) hist16[j] = 0u;
}

__global__ void histpick16_kernel(const u64* __restrict__ keys, Ctl* ctl,
                                  u32* __restrict__ hist16, u32* __restrict__ coarse,
                                  int shift, int nblocks) {
  __shared__ int lastflag;
  const int tid = threadIdx.x;
  u64 prefix = ctl->prefix;
  int i = blockIdx.x * 256 + tid;
  if (i < N_NODES) {
    u64 key = keys[i];
    if ((key >> (shift + 16)) == (prefix >> (shift + 16))) {
      atomicAdd(&hist16[(u32)(key >> shift) & 0xFFFFu], 1u);
      atomicAdd(&coarse[(u32)(key >> (shift + 8)) & 0xFFu], 1u);
    }
  }
  __syncthreads();
  if (tid == 0) {
    __threadfence();
    u32 old = atomicAdd(&ctl->done, 1u);
    lastflag = (old == (u32)(nblocks - 1));
  }
  __syncthreads();
  if (!lastflag) return;
  pick16_dev(ctl, hist16, coarse, shift);
}

// ------------- unified gather: 32 lanes/node, bf16x2 loads; ILP-4 -------------
// len==null: bounds from rowstart[d+1]; else i1 = rowstart[d] + len[d]

__global__ void agg_gather64_kernel(const bf16* __restrict__ hW, const int* __restrict__ rowstart,
                                    const int* __restrict__ len, const int* __restrict__ csr,
                                    const float* __restrict__ dis,
                                    const void* __restrict__ b, const Ctl* __restrict__ ctl,
                                    bf16* __restrict__ agg, int M, int relusrc, int addbias)
{
  const bool f32 = ctl->isfp32 != 0;
  int gid = blockIdx.x * 256 + threadIdx.x;
  int d = gid >> 5;
  int lane = gid & 31;
  if (d >= M) return;
  const bf16x2* H = (const bf16x2*)hW;
  float dd = dis[d];
  bf16x2 v = H[(size_t)d * 32 + lane];
  float ax = bf2f(v.x), ay = bf2f(v.y);
  if (relusrc) { ax = fmaxf(ax, 0.f); ay = fmaxf(ay, 0.f); }
  float sw = dd * dd;
  ax *= sw; ay *= sw;
  if (addbias) { ax += loadF(b, 2 * lane, f32); ay += loadF(b, 2 * lane + 1, f32); }
  int i = rowstart[d];
  int i1 = len ? (i + len[d]) : rowstart[d + 1];
  for (; i + 4 <= i1; i += 4) {
    int s0 = csr[i], s1 = csr[i + 1], s2 = csr[i + 2], s3 = csr[i + 3];
    float w0 = dd * dis[s0], w1 = dd * dis[s1], w2 = dd * dis[s2], w3 = dd * dis[s3];
    bf16x2 v0 = H[(size_t)s0 * 32 + lane];
    bf16x2 v1 = H[(size_t)s1 * 32 + lane];
    bf16x2 v2 = H[(size_t)s2 * 32 + lane];
    bf16x2 v3 = H[(size_t)s3 * 32 + lane];
    float x0 = bf2f(v0.x), y0 = bf2f(v0.y), x1 = bf2f(v1.x), y1 = bf2f(v1.y);
    float x2 = bf2f(v2.x), y2 = bf2f(v2.y), x3 = bf2f(v3.x), y3 = bf2f(v3.y);
    if (relusrc) {
      x0 = fmaxf(x0, 0.f); y0 = fmaxf(y0, 0.f); x1 = fmaxf(x1, 0.f); y1 = fmaxf(y1, 0.f);
      x2 = fmaxf(x2, 0.f); y2 = fmaxf(y2, 0.f); x3 = fmaxf(x3, 0.f); y3 = fmaxf(y3, 0.f);
    }
    ax += w0 * x0 + w1 * x1 + w2 * x2 + w3 * x3;
    ay += w0 * y0 + w1 * y1 + w2 * y2 + w3 * y3;
  }
  for (; i < i1; ++i) {
    int s = csr[i];
    float w = dd * dis[s];
    bf16x2 vv = H[(size_t)s * 32 + lane];
    float xx = bf2f(vv.x), yy = bf2f(vv.y);
    if (relusrc) { xx = fmaxf(xx, 0.f); yy = fmaxf(yy, 0.f); }
    ax += w * xx; ay += w * yy;
  }
  bf16x2 w2;
  w2.x = __float2bfloat16(ax);
  w2.y = __float2bfloat16(ay);
  ((bf16x2*)agg)[(size_t)d * 32 + lane] = w2;
}

// ---------------- MFMA GEMMs (16x16x32 bf16, fp32 acc) ----------------

// conv1: Y[N,128] = G[N,64] @ W1 + b1, fused pooling score/keys + radix pass-1 hist/pick
__global__ void gemm_in_kernel(const bf16* __restrict__ G, const void* __restrict__ W,
                               const void* __restrict__ b, const void* __restrict__ pw,
                               bf16* __restrict__ Y, Ctl* ctl,
                               float* __restrict__ score, u64* __restrict__ keys,
                               u32* __restrict__ hist16, u32* __restrict__ coarse, int nblocks)
{
  __shared__ short Xs[64 * 72];
  __shared__ short Wt[128 * 72];
  __shared__ float bs[128];
  __shared__ float ps[128];
  __shared__ int lastflag;
  const bool f32 = ctl->isfp32 != 0;
  const int tid = threadIdx.x;
  const int row0 = blockIdx.x * 64;

  for (int i = tid; i < 64 * 128; i += 256) {
    int k = i >> 7, n = i & 127;
    Wt[n * 72 + k] = f32 ? f2bf_bits(((const float*)W)[i]) : ((const short*)W)[i];
  }
  const u32* G2 = (const u32*)G;
  for (int p = tid; p < 64 * 32; p += 256) {
    int r = p >> 5, kp = p & 31;
    int gr = row0 + r;
    u32 v = (gr < N_NODES) ? G2[(size_t)gr * 32 + kp] : 0u;
    *(u32*)&Xs[r * 72 + 2 * kp] = v;
  }
  for (int i = tid; i < 128; i += 256) { bs[i] = loadF(b, i, f32); ps[i] = loadF(pw, i, f32); }
  __syncthreads();

  const int lane = tid & 63;
  const int w = tid >> 6;
  const int l16 = lane & 15;
  const int quad = lane >> 4;
  f32x4 acc[8];
  #pragma unroll
  for (int ct = 0; ct < 8; ++ct) acc[ct] = (f32x4){0.f, 0.f, 0.f, 0.f};
  const int arow = w * 16 + l16;
  #pragma unroll
  for (int kc = 0; kc < 2; ++kc) {
    short8 a = *(short8*)&Xs[arow * 72 + kc * 32 + quad * 8];
    #pragma unroll
    for (int ct = 0; ct < 8; ++ct) {
      short8 bb = *(short8*)&Wt[(ct * 16 + l16) * 72 + kc * 32 + quad * 8];
      acc[ct] = __builtin_amdgcn_mfma_f32_16x16x32_bf16(a, bb, acc[ct], 0, 0, 0);
    }
  }
  float inv_norm = ctl->inv_norm;
  #pragma unroll
  for (int r = 0; r < 4; ++r) {
    int gr = row0 + w * 16 + quad * 4 + r;
    float p = 0.f;
    #pragma unroll
    for (int ct = 0; ct < 8; ++ct) {
      int col = ct * 16 + l16;
      float h = acc[ct][r] + bs[col];
      if (gr < N_NODES) Y[(size_t)gr * 128 + col] = __float2bfloat16(h);
      p += fmaxf(h, 0.f) * ps[col];
    }
    p += __shfl_down(p, 8, 16);
    p += __shfl_down(p, 4, 16);
    p += __shfl_down(p, 2, 16);
    p += __shfl_down(p, 1, 16);
    if (l16 == 0 && gr < N_NODES) {
      float sc = tanhf(p * inv_norm);
      score[gr] = sc;
      u32 u = __float_as_uint(sc);
      u = (u & 0x80000000u) ? ~u : (u | 0x80000000u);
      u64 key = (((u64)u) << 16) | (u64)(0xFFFFu - (u32)gr);
      keys[gr] = key;
      atomicAdd(&hist16[(u32)(key >> 32) & 0xFFFFu], 1u);
      atomicAdd(&coarse[(u32)(key >> 40) & 0xFFu], 1u);
    }
  }
  // fused radix pass 1 (shift=32) pick by last-arriving block
  __syncthreads();
  if (tid == 0) {
    __threadfence();
    u32 old = atomicAdd(&ctl->done, 1u);
    lastflag = (old == (u32)(nblocks - 1));
  }
  __syncthreads();
  if (lastflag) pick16_dev(ctl, hist16, coarse, 32);
}

// Y[M,64] = (relu?)X[M,128] @ W[128,64]; M multiple of 64
// kept!=null: X row = kept[row], apply relu*score[kept[row]] (fused TopK hp)
__global__ void gemm_128_64_kernel(const bf16* __restrict__ X, const void* __restrict__ W,
                                   bf16* __restrict__ Y, const Ctl* __restrict__ ctl,
                                   int M, int relu_x,
                                   const int* __restrict__ kept, const float* __restrict__ score)
{
  __shared__ short Xs[64 * 136];
  __shared__ short Wt[64 * 136];
  __shared__ int keptS[64];
  __shared__ float scS[64];
  const bool f32 = ctl->isfp32 != 0;
  const int tid = threadIdx.x;
  const int row0 = blockIdx.x * 64;

  if (kept) {
    for (int i = tid; i < 64; i += 256) {
      int o = kept[row0 + i];
      keptS[i] = o;
      scS[i] = score[o];
    }
  }
  __syncthreads();

  for (int i = tid; i < 128 * 64; i += 256) {
    int k = i >> 6, n = i & 63;
    Wt[n * 136 + k] = f32 ? f2bf_bits(((const float*)W)[i]) : ((const short*)W)[i];
  }
  const u32* X2 = (const u32*)X;
  for (int p = tid; p < 64 * 64; p += 256) {
    int r = p >> 6, kp = p & 63;
    int srow = kept ? keptS[r] : (row0 + r);
    u32 v = X2[(size_t)srow * 64 + kp];
    if (relu_x) {
      if (v & 0x8000u) v &= 0xFFFF0000u;
      if (v & 0x80000000u) v &= 0x0000FFFFu;
    }
    if (kept) {
      bf16x2 h = *(bf16x2*)&v;
      float s = scS[r];
      bf16x2 o;
      o.x = __float2bfloat16(fmaxf(bf2f(h.x), 0.f) * s);
      o.y = __float2bfloat16(fmaxf(bf2f(h.y), 0.f) * s);
      v = *(u32*)&o;
    }
    *(u32*)&Xs[r * 136 + 2 * kp] = v;
  }
  __syncthreads();

  const int lane = tid & 63;
  const int w = tid >> 6;
  const int l16 = lane & 15;
  const int quad = lane >> 4;
  f32x4 acc[4];
  #pragma unroll
  for (int ct = 0; ct < 4; ++ct) acc[ct] = (f32x4){0.f, 0.f, 0.f, 0.f};
  const int arow = w * 16 + l16;
  #pragma unroll
  for (int kc = 0; kc < 4; ++kc) {
    short8 a = *(short8*)&Xs[arow * 136 + kc * 32 + quad * 8];
    #pragma unroll
    for (int ct = 0; ct < 4; ++ct) {
      short8 bb = *(short8*)&Wt[(ct * 16 + l16) * 136 + kc * 32 + quad * 8];
      acc[ct] = __builtin_amdgcn_mfma_f32_16x16x32_bf16(a, bb, acc[ct], 0, 0, 0);
    }
  }
  #pragma unroll
  for (int ct = 0; ct < 4; ++ct)
    #pragma unroll
    for (int r = 0; r < 4; ++r) {
      int gr = row0 + w * 16 + quad * 4 + r;
      Y[(size_t)gr * 64 + ct * 16 + l16] = __float2bfloat16(acc[ct][r]);
    }
}

// conv3: Y[M,128] = X[M,64] @ W[64,128] + b; M multiple of 64
__global__ void gemm_64_128_kernel(const bf16* __restrict__ X, const void* __restrict__ W,
                                   const void* __restrict__ b, bf16* __restrict__ Y,
                                   const Ctl* __restrict__ ctl, int M)
{
  __shared__ short Xs[64 * 72];
  __shared__ short Wt[128 * 72];
  __shared__ float bs[128];
  const bool f32 = ctl->isfp32 != 0;
  const int tid = threadIdx.x;
  const int row0 = blockIdx.x * 64;

  for (int i = tid; i < 64 * 128; i += 256) {
    int k = i >> 7, n = i & 127;
    Wt[n * 72 + k] = f32 ? f2bf_bits(((const float*)W)[i]) : ((const short*)W)[i];
  }
  const u32* X2 = (const u32*)X;
  for (int p = tid; p < 64 * 32; p += 256) {
    int r = p >> 5, kp = p & 31;
    *(u32*)&Xs[r * 72 + 2 * kp] = X2[(size_t)(row0 + r) * 32 + kp];
  }
  for (int i = tid; i < 128; i += 256) bs[i] = loadF(b, i, f32);
  __syncthreads();

  const int lane = tid & 63;
  const int w = tid >> 6;
  const int l16 = lane & 15;
  const int quad = lane >> 4;
  f32x4 acc[8];
  #pragma unroll
  for (int ct = 0; ct < 8; ++ct) acc[ct] = (f32x4){0.f, 0.f, 0.f, 0.f};
  const int arow = w * 16 + l16;
  #pragma unroll
  for (int kc = 0; kc < 2; ++kc) {
    short8 a = *(short8*)&Xs[arow * 72 + kc * 32 + quad * 8];
    #pragma unroll
    for (int ct = 0; ct < 8; ++ct) {
      short8 bb = *(short8*)&Wt[(ct * 16 + l16) * 72 + kc * 32 + quad * 8];
      acc[ct] = __builtin_amdgcn_mfma_f32_16x16x32_bf16(a, bb, acc[ct], 0, 0, 0);
    }
  }
  #pragma unroll
  for (int ct = 0; ct < 8; ++ct)
    #pragma unroll
    for (int r = 0; r < 4; ++r) {
      int gr = row0 + w * 16 + quad * 4 + r;
      int col = ct * 16 + l16;
      Y[(size_t)gr * 128 + col] = __float2bfloat16(acc[ct][r] + bs[col]);
    }
}

// conv4: gather + per-block mean-pool partial (grid-stride; bias folded into reduce)
__global__ void agg_gather64_final_kernel(const bf16* __restrict__ hW, const int* __restrict__ rowstart,
                                          const int* __restrict__ len, const int* __restrict__ csr,
                                          const float* __restrict__ dis,
                                          float* __restrict__ partial, int M, int nblk)
{
  __shared__ float cs[64];
  const int tid = threadIdx.x;
  if (tid < 64) cs[tid] = 0.f;
  __syncthreads();
  const int lane = tid & 31;
  const bf16x2* H = (const bf16x2*)hW;
  for (int d = (blockIdx.x * 256 + tid) >> 5; d < M; d += nblk * 8) {
    float dd = dis[d];
    bf16x2 v = H[(size_t)d * 32 + lane];
    float sw = dd * dd;
    float ax = bf2f(v.x) * sw, ay = bf2f(v.y) * sw;
    int i = rowstart[d];
    int i1 = i + len[d];
    for (; i + 4 <= i1; i += 4) {
      int s0 = csr[i], s1 = csr[i + 1], s2 = csr[i + 2], s3 = csr[i + 3];
      float w0 = dd * dis[s0], w1 = dd * dis[s1], w2 = dd * dis[s2], w3 = dd * dis[s3];
      bf16x2 v0 = H[(size_t)s0 * 32 + lane];
      bf16x2 v1 = H[(size_t)s1 * 32 + lane];
      bf16x2 v2 = H[(size_t)s2 * 32 + lane];
      bf16x2 v3 = H[(size_t)s3 * 32 + lane];
      ax += w0 * bf2f(v0.x) + w1 * bf2f(v1.x) + w2 * bf2f(v2.x) + w3 * bf2f(v3.x);
      ay += w0 * bf2f(v0.y) + w1 * bf2f(v1.y) + w2 * bf2f(v2.y) + w3 * bf2f(v3.y);
    }
    for (; i < i1; ++i) {
      int s = csr[i];
      float w = dd * dis[s];
      bf16x2 vv = H[(size_t)s * 32 + lane];
      ax += w * bf2f(vv.x);
      ay += w * bf2f(vv.y);
    }
    atomicAdd(&cs[2 * lane], ax);
    atomicAdd(&cs[2 * lane + 1], ay);
  }
  __syncthreads();
  if (tid < 64) partial[(size_t)tid * nblk + blockIdx.x] = cs[tid];
}

__global__ void reduce_out_kernel(const float* __restrict__ partial, const void* __restrict__ b,
                                  const Ctl* __restrict__ ctl, void* __restrict__ out, int nblk)
{
  __shared__ float sh[256];
  int c = blockIdx.x;
  float s = 0.f;
  for (int j = threadIdx.x; j < nblk; j += 256) s += partial[(size_t)c * nblk + j];
  sh[threadIdx.x] = s;
  __syncthreads();
  for (int st = 128; st > 0; st >>= 1) {
    if (threadIdx.x < st) sh[threadIdx.x] += sh[threadIdx.x + st];
    __syncthreads();
  }
  if (threadIdx.x == 0) {
    const bool f32 = ctl->isfp32 != 0;
    float val = sh[0] / (float)K_KEEP + loadF(b, c, f32);
    if (f32) ((float*)out)[c] = val;
    else     ((bf16*)out)[c] = __float2bfloat16(val);
  }
}

// ---------------- TopK mark ----------------

__global__ void mark_kernel(const u64* __restrict__ keys, Ctl* ctl,
                            int* __restrict__ new_idx, int* __restrict__ kept)
{
  int i = blockIdx.x * 256 + threadIdx.x;
  if (i >= N_NODES) return;
  if (keys[i] >= ctl->prefix) {
    int pos = (int)atomicAdd(&ctl->cnt, 1u);
    new_idx[i] = pos;
    kept[pos] = i;
  } else {
    new_idx[i] = -1;
  }
}

// ------- CSR2 in ONE kernel: count + wave-aggregated alloc + fill (order-free rows) -------

__global__ void csr2_build_kernel(const int* __restrict__ kept, const int* __restrict__ rowstart1,
                                  const int* __restrict__ csr1, const int* __restrict__ new_idx,
                                  Ctl* ctl, int* __restrict__ rowstart2, int* __restrict__ len2,
                                  float* __restrict__ dis2, int* __restrict__ csr2)
{
  int kp = blockIdx.x * 256 + threadIdx.x;
  int lane = threadIdx.x & 63;
  int c = 0;
  int i0 = 0, i1 = 0;
  if (kp < K_KEEP) {
    int o = kept[kp];
    i0 = rowstart1[o]; i1 = rowstart1[o + 1];
    int i = i0;
    for (; i + 4 <= i1; i += 4) {
      int s0 = csr1[i], s1 = csr1[i + 1], s2 = csr1[i + 2], s3 = csr1[i + 3];
      c += (new_idx[s0] >= 0) + (new_idx[s1] >= 0) + (new_idx[s2] >= 0) + (new_idx[s3] >= 0);
    }
    for (; i < i1; ++i) c += (new_idx[csr1[i]] >= 0);
  }
  // wave inclusive scan of c
  int pre = c;
  #pragma unroll
  for (int off = 1; off < 64; off <<= 1) {
    int t = __shfl_up(pre, off);
    if (lane >= off) pre += t;
  }
  int wtot = __shfl(pre, 63);
  int wbase = 0;
  if (lane == 0) wbase = (int)atomicAdd(&ctl->pad, (u32)wtot);
  wbase = __shfl(wbase, 0);
  int base = wbase + pre - c;
  if (kp < K_KEEP) {
    rowstart2[kp] = base;
    len2[kp] = c;
    dis2[kp] = rsqrtf(1.0f + (float)c);
    int w = base;
    for (int i = i0; i < i1; ++i) {
      int ns = new_idx[csr1[i]];
      if (ns >= 0) csr2[w++] = ns;
    }
  }
}

// ---------------- launch ----------------

extern "C" void kernel_launch(void* const* d_in, const int* in_sizes, int n_in,
                              void* d_out, int out_size, void* d_ws, size_t ws_size,
                              hipStream_t stream)
{
  const void* x  = d_in[0];
  const int*  ei = (const int*)d_in[1];
  const void* W1 = d_in[3];
  const void* b1 = d_in[4];
  const void* pw = d_in[5];
  const void* W2 = d_in[6];
  const void* b2 = d_in[7];
  const void* W3 = d_in[8];
  const void* b3 = d_in[9];
  const void* W4 = d_in[10];
  const void* b4 = d_in[11];

  const int* src = ei;
  const int* dst = ei + N_EDGES;

  float* F = (float*)d_ws;
  bf16*  A16       = (bf16*)F;               // N x 128 bf16
  bf16*  B16       = (bf16*)(F + 3200000);   // N x 128 bf16
  bf16*  C16       = (bf16*)(F + 6400000);   // K x 128 bf16 (also conv1's G [N x 64])
  u32*   xbf       = (u32*)(F + 9000000);    // N x 32 u32 (x as bf16 pairs)
  float* dis1      = F + 10600000;           // 50000
  float* dis2      = F + 10650000;           // 40000
  float* score     = F + 10690000;           // 50000
  u64*   keys      = (u64*)(F + 10740000);   // 50000 u64
  int*   new_idx   = (int*)(F + 10840000);   // 50000
  int*   kept      = (int*)(F + 10890000);   // 40000
  int*   len2      = (int*)(F + 10930000);   // 40000
  int*   rowstart1 = (int*)(F + 10970000);   // 50001
  int*   rowstart2 = (int*)(F + 11020004);   // 40000
  int*   csr1      = (int*)(F + 11060008);   // 800000
  int*   csr2      = (int*)(F + 11860008);   // 800000
  Ctl*   ctl       = (Ctl*)(F + 12660008);   // ~1.1 KB
  int*   boff      = (int*)(F + 12660600);   // 256
  int*   detcnt    = (int*)(F + 12660856);   // 64
  int*   bucket_cur= (int*)(F + 12660920);   // 196
  u32*   hist16    = (u32*)(F + 12661116);   // 65536
  u32*   coarse    = hist16 + 65536;         // 256 (contiguous, zeroed with hist16)
  u32*   bucketbuf = (u32*)(F + 12726908);   // 196*6144
  float* partial   = F + 13931132;           // 64 x 1024

  const int NB1 = (N_NODES + 255) / 256;     // 196
  const int EB2 = (N_EDGES + 2047) / 2048;   // 391
  const int GB1 = (N_NODES + 63) / 64;       // 782
  const int AB1 = N_NODES * 32 / 256;        // 6250
  const int ABK = K_KEEP * 32 / 256;         // 5000
  const int CB2 = (K_KEEP + 255) / 256;      // 157
  const int NBF = 1024;                      // final-gather blocks

  init_kernel<<<NB1, 256, 0, stream>>>((const unsigned short*)x, bucket_cur, detcnt, ctl, hist16);
  norm_kernel<<<1, 64, 0, stream>>>(pw, detcnt, ctl);

  // CSR graph 1 via bucket sort (+fused x->bf16 conversion)
  bucket_scatter_kernel<<<EB2, 256, 0, stream>>>(src, dst, bucket_cur, bucketbuf, x, xbf, ctl);
  scan_buckets_kernel<<<1, 256, 0, stream>>>(bucket_cur, boff, &rowstart1[N_NODES]);
  csr_from_buckets_kernel<<<BKT, 256, 0, stream>>>(bucketbuf, bucket_cur, boff, rowstart1, dis1, csr1);

  // conv1 (gather-first on bf16 x): G = A_norm . x ; h1 = G @ W1 + b1 (+fused score+radix pass1)
  agg_gather64_kernel<<<AB1, 256, 0, stream>>>((const bf16*)xbf, rowstart1, nullptr, csr1, dis1,
                                               nullptr, ctl, C16, N_NODES, 0, 0);
  gemm_in_kernel<<<GB1, 256, 0, stream>>>(C16, W1, b1, pw, B16, ctl, score, keys,
                                          hist16, coarse, GB1);

  // top-K select: remaining two 16-bit radix passes, then mark
  histpick16_kernel<<<NB1, 256, 0, stream>>>(keys, ctl, hist16, coarse, 16, NB1);
  histpick16_kernel<<<NB1, 256, 0, stream>>>(keys, ctl, hist16, coarse, 0, NB1);
  mark_kernel<<<NB1, 256, 0, stream>>>(keys, ctl, new_idx, kept);

  // CSR graph 2 in one kernel (row bases via wave-aggregated atomic; order-free)
  csr2_build_kernel<<<CB2, 256, 0, stream>>>(kept, rowstart1, csr1, new_idx, ctl,
                                             rowstart2, len2, dis2, csr2);

  // conv2: gemm-first (fused hp: relu*score on kept rows): A = hp @ W2 ; h2 = gather(A) + b2
  gemm_128_64_kernel<<<K_KEEP / 64, 256, 0, stream>>>(B16, W2, A16, ctl, K_KEEP, 0, kept, score);
  agg_gather64_kernel<<<ABK, 256, 0, stream>>>(A16, rowstart2, len2, csr2, dis2, b2, ctl, C16, K_KEEP, 0, 1);

  // conv3: gather-first: G = gather(relu(h2)) ; h3 = G @ W3 + b3
  agg_gather64_kernel<<<ABK, 256, 0, stream>>>(C16, rowstart2, len2, csr2, dis2, b3, ctl, A16, K_KEEP, 1, 0);
  gemm_64_128_kernel<<<K_KEEP / 64, 256, 0, stream>>>(A16, W3, b3, B16, ctl, K_KEEP);

  // conv4: gemm-first: A = relu(h3) @ W4 ; partials = gather(A) (b4 folded into reduce)
  gemm_128_64_kernel<<<K_KEEP / 64, 256, 0, stream>>>(B16, W4, A16, ctl, K_KEEP, 1, nullptr, nullptr);
  agg_gather64_final_kernel<<<NBF, 256, 0, stream>>>(A16, rowstart2, len2, csr2, dis2, partial, K_KEEP, NBF);

  reduce_out_kernel<<<64, 256, 0, stream>>>(partial, b4, ctl, d_out, NBF);
}

// Round 2
// 404.258 us; speedup vs baseline: 1.4323x; 1.4323x over previous
//
#include <hip/hip_runtime.h>
#include <hip/hip_bf16.h>
#include <stdint.h>

#define N_NODES 50000
#define N_EDGES 800000
#define K_KEEP  40000
#define BKT     196        // ceil(N_NODES/256) dst-range buckets
#define BCAP    6144       // per-bucket capacity (mean 4081, +32 sigma)

typedef unsigned long long u64;
typedef unsigned int u32;
typedef unsigned short u16;
typedef __hip_bfloat16 bf16;
typedef __hip_bfloat162 bf16x2;
typedef __attribute__((ext_vector_type(8))) short short8;
typedef __attribute__((ext_vector_type(4))) float f32x4;

struct Ctl {
  u64 prefix;
  u32 kremain;
  u32 cnt;
  float inv_norm;
  u32 isfp32;
  u32 done;
  u32 pad;          // csr2 edge cursor
  u32 hist[256];    // radix histogram (LDS-aggregated flushes only)
};

__device__ __forceinline__ float bf2f(bf16 v) { return __bfloat162float(v); }
__device__ __forceinline__ float loadF(const void* p, size_t i, bool f32) {
  return f32 ? ((const float*)p)[i] : bf2f(((const bf16*)p)[i]);
}
__device__ __forceinline__ short f2bf_bits(float f) {
  bf16 t = __float2bfloat16(f);
  return *(const short*)&t;
}

// ---------------- init (+parallel dtype detect, proven R5-R8) ----------------

__global__ void init_kernel(const unsigned short* __restrict__ x16,
                            int* __restrict__ bucket_cur, int* __restrict__ detcnt, Ctl* ctl) {
  __shared__ u32 dsh[256];
  int i = blockIdx.x * 256 + threadIdx.x;
  if (i < BKT) bucket_cur[i] = i * BCAP;
  if (blockIdx.x == 0) {
    ctl->hist[threadIdx.x] = 0u;
    if (threadIdx.x == 0) {
      ctl->prefix = 0ull; ctl->kremain = K_KEEP; ctl->cnt = 0u; ctl->done = 0u; ctl->pad = 0u;
    }
  }
  if (blockIdx.x < 64) {
    int base = blockIdx.x * 2048;
    u32 c = 0;
    for (int j = threadIdx.x; j < 2048; j += 256) {
      u32 h = x16[base + j];
      if ((h & 0x7F80u) == 0x7F80u) c++;
    }
    dsh[threadIdx.x] = c;
    __syncthreads();
    for (int s = 128; s > 0; s >>= 1) {
      if (threadIdx.x < s) dsh[threadIdx.x] += dsh[threadIdx.x + s];
      __syncthreads();
    }
    if (threadIdx.x == 0) detcnt[blockIdx.x] = (int)dsh[0];
  }
}

__global__ void norm_kernel(const void* __restrict__ pw, const int* __restrict__ detcnt, Ctl* ctl) {
  int lane = threadIdx.x;   // 64
  int dc = detcnt[lane];
  for (int off = 32; off; off >>= 1) dc += __shfl_down(dc, off);
  dc = __shfl(dc, 0);
  bool f32 = (dc >= 16);
  float v0 = loadF(pw, lane, f32);
  float v1 = loadF(pw, 64 + lane, f32);
  float s = v0 * v0 + v1 * v1;
  for (int off = 32; off; off >>= 1) s += __shfl_down(s, off);
  if (lane == 0) {
    ctl->inv_norm = 1.0f / sqrtf(s);
    ctl->isfp32 = f32 ? 1u : 0u;
  }
}

// ------------- CSR1 via bucket sort (proven R8) + fp32->bf16 convert (only if needed) -------------

__global__ void bucket_scatter_kernel(const int* __restrict__ src, const int* __restrict__ dst,
                                      int* __restrict__ bucket_cur, u32* __restrict__ bucketbuf,
                                      const void* __restrict__ x, u32* __restrict__ xbf,
                                      const Ctl* __restrict__ ctl)
{
  __shared__ u32 hist[BKT];
  __shared__ u32 base[BKT];
  const int tid = threadIdx.x;
  const int e0 = blockIdx.x * 2048;
  for (int t = tid; t < BKT; t += 256) hist[t] = 0;
  __syncthreads();
  #pragma unroll
  for (int j = 0; j < 8; ++j) {
    int e = e0 + j * 256 + tid;
    if (e < N_EDGES) atomicAdd(&hist[dst[e] >> 8], 1u);
  }
  __syncthreads();
  for (int t = tid; t < BKT; t += 256) {
    u32 c = hist[t];
    base[t] = c ? (u32)atomicAdd(&bucket_cur[t], (int)c) : 0u;
    hist[t] = 0;
  }
  __syncthreads();
  #pragma unroll
  for (int j = 0; j < 8; ++j) {
    int e = e0 + j * 256 + tid;
    if (e < N_EDGES) {
      int d = dst[e];
      int b = d >> 8;
      u32 pos = base[b] + atomicAdd(&hist[b], 1u);
      bucketbuf[pos] = ((u32)src[e] << 8) | (u32)(d & 255);
    }
  }
  // fused x -> bf16 (pair) conversion; only when input is fp32
  if (ctl->isfp32 != 0) {
    const int p0 = blockIdx.x * 4096;
    const float2* xf = (const float2*)x;
    for (int j = tid; j < 4096; j += 256) {
      int p = p0 + j;
      if (p < N_NODES * 32) {
        float2 v = xf[p];
        u32 w = ((u32)(u16)f2bf_bits(v.y) << 16) | (u32)(u16)f2bf_bits(v.x);
        xbf[p] = w;
      }
    }
  }
}

__global__ void scan_buckets_kernel(const int* __restrict__ bucket_cur, int* __restrict__ boff,
                                    int* __restrict__ rowstart_n)
{
  __shared__ int sh[256];
  int tid = threadIdx.x;
  int v = (tid < BKT) ? (bucket_cur[tid] - tid * BCAP) : 0;
  sh[tid] = v;
  __syncthreads();
  for (int off = 1; off < 256; off <<= 1) {
    int t = (tid >= off) ? sh[tid - off] : 0;
    __syncthreads();
    sh[tid] += t;
    __syncthreads();
  }
  if (tid < BKT) boff[tid] = sh[tid] - v;
  if (tid == 255) *rowstart_n = sh[255];
}

__global__ void csr_from_buckets_kernel(const u32* __restrict__ bucketbuf, const int* __restrict__ bucket_cur,
                                        const int* __restrict__ boff, int* __restrict__ rowstart,
                                        float* __restrict__ dis, int* __restrict__ csr)
{
  __shared__ u32 cnt[256];
  __shared__ u32 loc[256];
  __shared__ u32 cur[256];
  const int b = blockIdx.x;
  const int tid = threadIdx.x;
  const int bc = bucket_cur[b] - b * BCAP;
  const u32* buf = bucketbuf + (size_t)b * BCAP;
  const int off0 = boff[b];
  cnt[tid] = 0;
  __syncthreads();
  for (int i = tid; i < bc; i += 256) atomicAdd(&cnt[buf[i] & 255u], 1u);
  __syncthreads();
  u32 c = cnt[tid];
  loc[tid] = c;
  __syncthreads();
  for (int off = 1; off < 256; off <<= 1) {
    u32 t = (tid >= off) ? loc[tid - off] : 0;
    __syncthreads();
    loc[tid] += t;
    __syncthreads();
  }
  int node = b * 256 + tid;
  u32 excl = loc[tid] - c;
  if (node < N_NODES) {
    rowstart[node] = off0 + (int)excl;
    dis[node] = rsqrtf(1.0f + (float)c);
  }
  cur[tid] = off0 + excl;
  __syncthreads();
  for (int i = tid; i < bc; i += 256) {
    u32 p = buf[i];
    u32 pos = atomicAdd(&cur[p & 255u], 1u);
    csr[pos] = (int)(p >> 8);
  }
}

// ------------- unified gather: 32 lanes/node, bf16x2 loads; ILP-4 -------------
// len==null: bounds from rowstart[d+1]; else i1 = rowstart[d] + len[d]
// data source = isfp32 ? hWalt : hW  (conv1 passes x / xbf; others pass same ptr twice)

__global__ void agg_gather64_kernel(const bf16* __restrict__ hW, const bf16* __restrict__ hWalt,
                                    const int* __restrict__ rowstart,
                                    const int* __restrict__ len, const int* __restrict__ csr,
                                    const float* __restrict__ dis,
                                    const void* __restrict__ b, const Ctl* __restrict__ ctl,
                                    bf16* __restrict__ agg, int M, int relusrc, int addbias)
{
  const bool f32 = ctl->isfp32 != 0;
  int gid = blockIdx.x * 256 + threadIdx.x;
  int d = gid >> 5;
  int lane = gid & 31;
  if (d >= M) return;
  const bf16x2* H = (const bf16x2*)(f32 ? hWalt : hW);
  float dd = dis[d];
  bf16x2 v = H[(size_t)d * 32 + lane];
  float ax = bf2f(v.x), ay = bf2f(v.y);
  if (relusrc) { ax = fmaxf(ax, 0.f); ay = fmaxf(ay, 0.f); }
  float sw = dd * dd;
  ax *= sw; ay *= sw;
  if (addbias) { ax += loadF(b, 2 * lane, f32); ay += loadF(b, 2 * lane + 1, f32); }
  int i = rowstart[d];
  int i1 = len ? (i + len[d]) : rowstart[d + 1];
  for (; i + 4 <= i1; i += 4) {
    int s0 = csr[i], s1 = csr[i + 1], s2 = csr[i + 2], s3 = csr[i + 3];
    float w0 = dd * dis[s0], w1 = dd * dis[s1], w2 = dd * dis[s2], w3 = dd * dis[s3];
    bf16x2 v0 = H[(size_t)s0 * 32 + lane];
    bf16x2 v1 = H[(size_t)s1 * 32 + lane];
    bf16x2 v2 = H[(size_t)s2 * 32 + lane];
    bf16x2 v3 = H[(size_t)s3 * 32 + lane];
    float x0 = bf2f(v0.x), y0 = bf2f(v0.y), x1 = bf2f(v1.x), y1 = bf2f(v1.y);
    float x2 = bf2f(v2.x), y2 = bf2f(v2.y), x3 = bf2f(v3.x), y3 = bf2f(v3.y);
    if (relusrc) {
      x0 = fmaxf(x0, 0.f); y0 = fmaxf(y0, 0.f); x1 = fmaxf(x1, 0.f); y1 = fmaxf(y1, 0.f);
      x2 = fmaxf(x2, 0.f); y2 = fmaxf(y2, 0.f); x3 = fmaxf(x3, 0.f); y3 = fmaxf(y3, 0.f);
    }
    ax += w0 * x0 + w1 * x1 + w2 * x2 + w3 * x3;
    ay += w0 * y0 + w1 * y1 + w2 * y2 + w3 * y3;
  }
  for (; i < i1; ++i) {
    int s = csr[i];
    float w = dd * dis[s];
    bf16x2 vv = H[(size_t)s * 32 + lane];
    float xx = bf2f(vv.x), yy = bf2f(vv.y);
    if (relusrc) { xx = fmaxf(xx, 0.f); yy = fmaxf(yy, 0.f); }
    ax += w * xx; ay += w * yy;
  }
  bf16x2 w2;
  w2.x = __float2bfloat16(ax);
  w2.y = __float2bfloat16(ay);
  ((bf16x2*)agg)[(size_t)d * 32 + lane] = w2;
}

// ---------------- MFMA GEMMs (16x16x32 bf16, fp32 acc) ----------------

// conv1: Y[N,128] = G[N,64] @ W1 + b1, fused pooling score/keys (clean — no histograms)
__global__ void gemm_in_kernel(const bf16* __restrict__ G, const void* __restrict__ W,
                               const void* __restrict__ b, const void* __restrict__ pw,
                               bf16* __restrict__ Y, const Ctl* __restrict__ ctl,
                               float* __restrict__ score, u64* __restrict__ keys)
{
  __shared__ short Xs[64 * 72];
  __shared__ short Wt[128 * 72];
  __shared__ float bs[128];
  __shared__ float ps[128];
  const bool f32 = ctl->isfp32 != 0;
  const int tid = threadIdx.x;
  const int row0 = blockIdx.x * 64;

  for (int i = tid; i < 64 * 128; i += 256) {
    int k = i >> 7, n = i & 127;
    Wt[n * 72 + k] = f32 ? f2bf_bits(((const float*)W)[i]) : ((const short*)W)[i];
  }
  const u32* G2 = (const u32*)G;
  for (int p = tid; p < 64 * 32; p += 256) {
    int r = p >> 5, kp = p & 31;
    int gr = row0 + r;
    u32 v = (gr < N_NODES) ? G2[(size_t)gr * 32 + kp] : 0u;
    *(u32*)&Xs[r * 72 + 2 * kp] = v;
  }
  for (int i = tid; i < 128; i += 256) { bs[i] = loadF(b, i, f32); ps[i] = loadF(pw, i, f32); }
  __syncthreads();

  const int lane = tid & 63;
  const int w = tid >> 6;
  const int l16 = lane & 15;
  const int quad = lane >> 4;
  f32x4 acc[8];
  #pragma unroll
  for (int ct = 0; ct < 8; ++ct) acc[ct] = (f32x4){0.f, 0.f, 0.f, 0.f};
  const int arow = w * 16 + l16;
  #pragma unroll
  for (int kc = 0; kc < 2; ++kc) {
    short8 a = *(short8*)&Xs[arow * 72 + kc * 32 + quad * 8];
    #pragma unroll
    for (int ct = 0; ct < 8; ++ct) {
      short8 bb = *(short8*)&Wt[(ct * 16 + l16) * 72 + kc * 32 + quad * 8];
      acc[ct] = __builtin_amdgcn_mfma_f32_16x16x32_bf16(a, bb, acc[ct], 0, 0, 0);
    }
  }
  float inv_norm = ctl->inv_norm;
  #pragma unroll
  for (int r = 0; r < 4; ++r) {
    int gr = row0 + w * 16 + quad * 4 + r;
    float p = 0.f;
    #pragma unroll
    for (int ct = 0; ct < 8; ++ct) {
      int col = ct * 16 + l16;
      float h = acc[ct][r] + bs[col];
      if (gr < N_NODES) Y[(size_t)gr * 128 + col] = __float2bfloat16(h);
      p += fmaxf(h, 0.f) * ps[col];
    }
    p += __shfl_down(p, 8, 16);
    p += __shfl_down(p, 4, 16);
    p += __shfl_down(p, 2, 16);
    p += __shfl_down(p, 1, 16);
    if (l16 == 0 && gr < N_NODES) {
      float sc = tanhf(p * inv_norm);
      score[gr] = sc;
      u32 u = __float_as_uint(sc);
      u = (u & 0x80000000u) ? ~u : (u | 0x80000000u);
      keys[gr] = (((u64)u) << 16) | (u64)(0xFFFFu - (u32)gr);
    }
  }
}

// Y[M,64] = (relu?)X[M,128] @ W[128,64]; M multiple of 64
// kept!=null: X row = kept[row], apply relu*score[kept[row]] (fused TopK hp)
__global__ void gemm_128_64_kernel(const bf16* __restrict__ X, const void* __restrict__ W,
                                   bf16* __restrict__ Y, const Ctl* __restrict__ ctl,
                                   int M, int relu_x,
                                   const int* __restrict__ kept, const float* __restrict__ score)
{
  __shared__ short Xs[64 * 136];
  __shared__ short Wt[64 * 136];
  __shared__ int keptS[64];
  __shared__ float scS[64];
  const bool f32 = ctl->isfp32 != 0;
  const int tid = threadIdx.x;
  const int row0 = blockIdx.x * 64;

  if (kept) {
    for (int i = tid; i < 64; i += 256) {
      int o = kept[row0 + i];
      keptS[i] = o;
      scS[i] = score[o];
    }
  }
  __syncthreads();

  for (int i = tid; i < 128 * 64; i += 256) {
    int k = i >> 6, n = i & 63;
    Wt[n * 136 + k] = f32 ? f2bf_bits(((const float*)W)[i]) : ((const short*)W)[i];
  }
  const u32* X2 = (const u32*)X;
  for (int p = tid; p < 64 * 64; p += 256) {
    int r = p >> 6, kp = p & 63;
    int srow = kept ? keptS[r] : (row0 + r);
    u32 v = X2[(size_t)srow * 64 + kp];
    if (relu_x) {
      if (v & 0x8000u) v &= 0xFFFF0000u;
      if (v & 0x80000000u) v &= 0x0000FFFFu;
    }
    if (kept) {
      bf16x2 h = *(bf16x2*)&v;
      float s = scS[r];
      bf16x2 o;
      o.x = __float2bfloat16(fmaxf(bf2f(h.x), 0.f) * s);
      o.y = __float2bfloat16(fmaxf(bf2f(h.y), 0.f) * s);
      v = *(u32*)&o;
    }
    *(u32*)&Xs[r * 136 + 2 * kp] = v;
  }
  __syncthreads();

  const int lane = tid & 63;
  const int w = tid >> 6;
  const int l16 = lane & 15;
  const int quad = lane >> 4;
  f32x4 acc[4];
  #pragma unroll
  for (int ct = 0; ct < 4; ++ct) acc[ct] = (f32x4){0.f, 0.f, 0.f, 0.f};
  const int arow = w * 16 + l16;
  #pragma unroll
  for (int kc = 0; kc < 4; ++kc) {
    short8 a = *(short8*)&Xs[arow * 136 + kc * 32 + quad * 8];
    #pragma unroll
    for (int ct = 0; ct < 4; ++ct) {
      short8 bb = *(short8*)&Wt[(ct * 16 + l16) * 136 + kc * 32 + quad * 8];
      acc[ct] = __builtin_amdgcn_mfma_f32_16x16x32_bf16(a, bb, acc[ct], 0, 0, 0);
    }
  }
  #pragma unroll
  for (int ct = 0; ct < 4; ++ct)
    #pragma unroll
    for (int r = 0; r < 4; ++r) {
      int gr = row0 + w * 16 + quad * 4 + r;
      Y[(size_t)gr * 64 + ct * 16 + l16] = __float2bfloat16(acc[ct][r]);
    }
}

// conv3: Y[M,128] = X[M,64] @ W[64,128] + b; M multiple of 64
__global__ void gemm_64_128_kernel(const bf16* __restrict__ X, const void* __restrict__ W,
                                   const void* __restrict__ b, bf16* __restrict__ Y,
                                   const Ctl* __restrict__ ctl, int M)
{
  __shared__ short Xs[64 * 72];
  __shared__ short Wt[128 * 72];
  __shared__ float bs[128];
  const bool f32 = ctl->isfp32 != 0;
  const int tid = threadIdx.x;
  const int row0 = blockIdx.x * 64;

  for (int i = tid; i < 64 * 128; i += 256) {
    int k = i >> 7, n = i & 127;
    Wt[n * 72 + k] = f32 ? f2bf_bits(((const float*)W)[i]) : ((const short*)W)[i];
  }
  const u32* X2 = (const u32*)X;
  for (int p = tid; p < 64 * 32; p += 256) {
    int r = p >> 5, kp = p & 31;
    *(u32*)&Xs[r * 72 + 2 * kp] = X2[(size_t)(row0 + r) * 32 + kp];
  }
  for (int i = tid; i < 128; i += 256) bs[i] = loadF(b, i, f32);
  __syncthreads();

  const int lane = tid & 63;
  const int w = tid >> 6;
  const int l16 = lane & 15;
  const int quad = lane >> 4;
  f32x4 acc[8];
  #pragma unroll
  for (int ct = 0; ct < 8; ++ct) acc[ct] = (f32x4){0.f, 0.f, 0.f, 0.f};
  const int arow = w * 16 + l16;
  #pragma unroll
  for (int kc = 0; kc < 2; ++kc) {
    short8 a = *(short8*)&Xs[arow * 72 + kc * 32 + quad * 8];
    #pragma unroll
    for (int ct = 0; ct < 8; ++ct) {
      short8 bb = *(short8*)&Wt[(ct * 16 + l16) * 72 + kc * 32 + quad * 8];
      acc[ct] = __builtin_amdgcn_mfma_f32_16x16x32_bf16(a, bb, acc[ct], 0, 0, 0);
    }
  }
  #pragma unroll
  for (int ct = 0; ct < 8; ++ct)
    #pragma unroll
    for (int r = 0; r < 4; ++r) {
      int gr = row0 + w * 16 + quad * 4 + r;
      int col = ct * 16 + l16;
      Y[(size_t)gr * 128 + col] = __float2bfloat16(acc[ct][r] + bs[col]);
    }
}

// conv4: gather + per-block mean-pool partial (grid-stride; bias folded into reduce)
__global__ void agg_gather64_final_kernel(const bf16* __restrict__ hW, const int* __restrict__ rowstart,
                                          const int* __restrict__ len, const int* __restrict__ csr,
                                          const float* __restrict__ dis,
                                          float* __restrict__ partial, int M, int nblk)
{
  __shared__ float cs[64];
  const int tid = threadIdx.x;
  if (tid < 64) cs[tid] = 0.f;
  __syncthreads();
  const int lane = tid & 31;
  const bf16x2* H = (const bf16x2*)hW;
  for (int d = (blockIdx.x * 256 + tid) >> 5; d < M; d += nblk * 8) {
    float dd = dis[d];
    bf16x2 v = H[(size_t)d * 32 + lane];
    float sw = dd * dd;
    float ax = bf2f(v.x) * sw, ay = bf2f(v.y) * sw;
    int i = rowstart[d];
    int i1 = i + len[d];
    for (; i + 4 <= i1; i += 4) {
      int s0 = csr[i], s1 = csr[i + 1], s2 = csr[i + 2], s3 = csr[i + 3];
      float w0 = dd * dis[s0], w1 = dd * dis[s1], w2 = dd * dis[s2], w3 = dd * dis[s3];
      bf16x2 v0 = H[(size_t)s0 * 32 + lane];
      bf16x2 v1 = H[(size_t)s1 * 32 + lane];
      bf16x2 v2 = H[(size_t)s2 * 32 + lane];
      bf16x2 v3 = H[(size_t)s3 * 32 + lane];
      ax += w0 * bf2f(v0.x) + w1 * bf2f(v1.x) + w2 * bf2f(v2.x) + w3 * bf2f(v3.x);
      ay += w0 * bf2f(v0.y) + w1 * bf2f(v1.y) + w2 * bf2f(v2.y) + w3 * bf2f(v3.y);
    }
    for (; i < i1; ++i) {
      int s = csr[i];
      float w = dd * dis[s];
      bf16x2 vv = H[(size_t)s * 32 + lane];
      ax += w * bf2f(vv.x);
      ay += w * bf2f(vv.y);
    }
    atomicAdd(&cs[2 * lane], ax);
    atomicAdd(&cs[2 * lane + 1], ay);
  }
  __syncthreads();
  if (tid < 64) partial[(size_t)tid * nblk + blockIdx.x] = cs[tid];
}

__global__ void reduce_out_kernel(const float* __restrict__ partial, const void* __restrict__ b,
                                  const Ctl* __restrict__ ctl, void* __restrict__ out, int nblk)
{
  __shared__ float sh[256];
  int c = blockIdx.x;
  float s = 0.f;
  for (int j = threadIdx.x; j < nblk; j += 256) s += partial[(size_t)c * nblk + j];
  sh[threadIdx.x] = s;
  __syncthreads();
  for (int st = 128; st > 0; st >>= 1) {
    if (threadIdx.x < st) sh[threadIdx.x] += sh[threadIdx.x + st];
    __syncthreads();
  }
  if (threadIdx.x == 0) {
    const bool f32 = ctl->isfp32 != 0;
    float val = sh[0] / (float)K_KEEP + loadF(b, c, f32);
    if (f32) ((float*)out)[c] = val;
    else     ((bf16*)out)[c] = __float2bfloat16(val);
  }
}

// ---------------- TopK select (proven R0 fused hist+pick, 8-bit, LDS-aggregated) ----------------

__global__ void histpick_kernel(const u64* __restrict__ keys, Ctl* ctl, int shift, int nblocks) {
  __shared__ u32 lh[256];
  __shared__ int lastflag;
  const int tid = threadIdx.x;
  lh[tid] = 0;
  __syncthreads();
  u64 prefix = ctl->prefix;
  int i = blockIdx.x * 256 + tid;
  if (i < N_NODES) {
    u64 key = keys[i];
    if ((key >> (shift + 8)) == (prefix >> (shift + 8)))
      atomicAdd(&lh[(u32)((key >> shift) & 0xFF)], 1u);
  }
  __syncthreads();
  u32 c = lh[tid];
  if (c) atomicAdd(&ctl->hist[tid], c);
  __syncthreads();
  if (tid == 0) {
    __threadfence();
    u32 old = atomicAdd(&ctl->done, 1u);
    lastflag = (old == (u32)(nblocks - 1));
  }
  __syncthreads();
  if (!lastflag) return;
  lh[tid] = atomicExch(&ctl->hist[tid], 0u);
  __syncthreads();
  if (tid == 0) {
    u32 kr = ctl->kremain;
    u32 cum = 0;
    int sel = 0;
    for (int v = 255; v >= 0; --v) {
      u32 cc = lh[v];
      if (cum + cc >= kr) { sel = v; break; }
      cum += cc;
    }
    ctl->prefix = prefix | (((u64)sel) << shift);
    ctl->kremain = kr - cum;
    ctl->done = 0u;
  }
}

__global__ void mark_kernel(const u64* __restrict__ keys, Ctl* ctl,
                            int* __restrict__ new_idx, int* __restrict__ kept)
{
  int i = blockIdx.x * 256 + threadIdx.x;
  if (i >= N_NODES) return;
  if (keys[i] >= ctl->prefix) {
    int pos = (int)atomicAdd(&ctl->cnt, 1u);
    new_idx[i] = pos;
    kept[pos] = i;
  } else {
    new_idx[i] = -1;
  }
}

// ------- CSR2 in ONE kernel: count + wave-aggregated alloc + fill (order-free rows) -------

__global__ void csr2_build_kernel(const int* __restrict__ kept, const int* __restrict__ rowstart1,
                                  const int* __restrict__ csr1, const int* __restrict__ new_idx,
                                  Ctl* ctl, int* __restrict__ rowstart2, int* __restrict__ len2,
                                  float* __restrict__ dis2, int* __restrict__ csr2)
{
  int kp = blockIdx.x * 256 + threadIdx.x;
  int lane = threadIdx.x & 63;
  int c = 0;
  int i0 = 0, i1 = 0;
  if (kp < K_KEEP) {
    int o = kept[kp];
    i0 = rowstart1[o]; i1 = rowstart1[o + 1];
    int i = i0;
    for (; i + 4 <= i1; i += 4) {
      int s0 = csr1[i], s1 = csr1[i + 1], s2 = csr1[i + 2], s3 = csr1[i + 3];
      c += (new_idx[s0] >= 0) + (new_idx[s1] >= 0) + (new_idx[s2] >= 0) + (new_idx[s3] >= 0);
    }
    for (; i < i1; ++i) c += (new_idx[csr1[i]] >= 0);
  }
  // wave inclusive scan of c
  int pre = c;
  #pragma unroll
  for (int off = 1; off < 64; off <<= 1) {
    int t = __shfl_up(pre, off);
    if (lane >= off) pre += t;
  }
  int wtot = __shfl(pre, 63);
  int wbase = 0;
  if (lane == 0) wbase = (int)atomicAdd(&ctl->pad, (u32)wtot);
  wbase = __shfl(wbase, 0);
  int base = wbase + pre - c;
  if (kp < K_KEEP) {
    rowstart2[kp] = base;
    len2[kp] = c;
    dis2[kp] = rsqrtf(1.0f + (float)c);
    int w = base;
    for (int i = i0; i < i1; ++i) {
      int ns = new_idx[csr1[i]];
      if (ns >= 0) csr2[w++] = ns;
    }
  }
}

// ---------------- launch ----------------

extern "C" void kernel_launch(void* const* d_in, const int* in_sizes, int n_in,
                              void* d_out, int out_size, void* d_ws, size_t ws_size,
                              hipStream_t stream)
{
  const void* x  = d_in[0];
  const int*  ei = (const int*)d_in[1];
  const void* W1 = d_in[3];
  const void* b1 = d_in[4];
  const void* pw = d_in[5];
  const void* W2 = d_in[6];
  const void* b2 = d_in[7];
  const void* W3 = d_in[8];
  const void* b3 = d_in[9];
  const void* W4 = d_in[10];
  const void* b4 = d_in[11];

  const int* src = ei;
  const int* dst = ei + N_EDGES;

  float* F = (float*)d_ws;
  bf16*  A16       = (bf16*)F;               // N x 128 bf16
  bf16*  B16       = (bf16*)(F + 3200000);   // N x 128 bf16
  bf16*  C16       = (bf16*)(F + 6400000);   // K x 128 bf16 (also conv1's G [N x 64])
  u32*   xbf       = (u32*)(F + 9000000);    // N x 32 u32 (x as bf16 pairs, only if fp32 input)
  float* dis1      = F + 10600000;           // 50000
  float* dis2      = F + 10650000;           // 40000
  float* score     = F + 10690000;           // 50000
  u64*   keys      = (u64*)(F + 10740000);   // 50000 u64
  int*   new_idx   = (int*)(F + 10840000);   // 50000
  int*   kept      = (int*)(F + 10890000);   // 40000
  int*   len2      = (int*)(F + 10930000);   // 40000
  int*   rowstart1 = (int*)(F + 10970000);   // 50001
  int*   rowstart2 = (int*)(F + 11020004);   // 40000
  int*   csr1      = (int*)(F + 11060008);   // 800000
  int*   csr2      = (int*)(F + 11860008);   // 800000
  Ctl*   ctl       = (Ctl*)(F + 12660008);   // ~1.1 KB
  int*   boff      = (int*)(F + 12660600);   // 256
  int*   detcnt    = (int*)(F + 12660856);   // 64
  int*   bucket_cur= (int*)(F + 12660920);   // 196
  u32*   bucketbuf = (u32*)(F + 12726908);   // 196*6144
  float* partial   = F + 13931132;           // 64 x 1024

  const int NB1 = (N_NODES + 255) / 256;     // 196
  const int EB2 = (N_EDGES + 2047) / 2048;   // 391
  const int GB1 = (N_NODES + 63) / 64;       // 782
  const int AB1 = N_NODES * 32 / 256;        // 6250
  const int ABK = K_KEEP * 32 / 256;         // 5000
  const int CB2 = (K_KEEP + 255) / 256;      // 157
  const int NBF = 1024;                      // final-gather blocks

  init_kernel<<<NB1, 256, 0, stream>>>((const unsigned short*)x, bucket_cur, detcnt, ctl);
  norm_kernel<<<1, 64, 0, stream>>>(pw, detcnt, ctl);

  // CSR graph 1 via bucket sort (+x->bf16 conversion iff fp32 input)
  bucket_scatter_kernel<<<EB2, 256, 0, stream>>>(src, dst, bucket_cur, bucketbuf, x, xbf, ctl);
  scan_buckets_kernel<<<1, 256, 0, stream>>>(bucket_cur, boff, &rowstart1[N_NODES]);
  csr_from_buckets_kernel<<<BKT, 256, 0, stream>>>(bucketbuf, bucket_cur, boff, rowstart1, dis1, csr1);

  // conv1 (gather-first on bf16 x): G = A_norm . x ; h1 = G @ W1 + b1 (+fused score/keys)
  agg_gather64_kernel<<<AB1, 256, 0, stream>>>((const bf16*)x, (const bf16*)xbf, rowstart1, nullptr,
                                               csr1, dis1, nullptr, ctl, C16, N_NODES, 0, 0);
  gemm_in_kernel<<<GB1, 256, 0, stream>>>(C16, W1, b1, pw, B16, ctl, score, keys);

  // top-K select (6 x 8-bit radix over 48-bit keys; LDS-aggregated hist — proven)
  for (int p = 0; p < 6; ++p)
    histpick_kernel<<<NB1, 256, 0, stream>>>(keys, ctl, 40 - 8 * p, NB1);
  mark_kernel<<<NB1, 256, 0, stream>>>(keys, ctl, new_idx, kept);

  // CSR graph 2 in one kernel (row bases via wave-aggregated atomic; order-free)
  csr2_build_kernel<<<CB2, 256, 0, stream>>>(kept, rowstart1, csr1, new_idx, ctl,
                                             rowstart2, len2, dis2, csr2);

  // conv2: gemm-first (fused hp: relu*score on kept rows): A = hp @ W2 ; h2 = gather(A) + b2
  gemm_128_64_kernel<<<K_KEEP / 64, 256, 0, stream>>>(B16, W2, A16, ctl, K_KEEP, 0, kept, score);
  agg_gather64_kernel<<<ABK, 256, 0, stream>>>(A16, A16, rowstart2, len2, csr2, dis2, b2, ctl, C16, K_KEEP, 0, 1);

  // conv3: gather-first: G = gather(relu(h2)) ; h3 = G @ W3 + b3
  agg_gather64_kernel<<<ABK, 256, 0, stream>>>(C16, C16, rowstart2, len2, csr2, dis2, b3, ctl, A16, K_KEEP, 1, 0);
  gemm_64_128_kernel<<<K_KEEP / 64, 256, 0, stream>>>(A16, W3, b3, B16, ctl, K_KEEP);

  // conv4: gemm-first: A = relu(h3) @ W4 ; partials = gather(A) (b4 folded into reduce)
  gemm_128_64_kernel<<<K_KEEP / 64, 256, 0, stream>>>(B16, W4, A16, ctl, K_KEEP, 1, nullptr, nullptr);
  agg_gather64_final_kernel<<<NBF, 256, 0, stream>>>(A16, rowstart2, len2, csr2, dis2, partial, K_KEEP, NBF);

  reduce_out_kernel<<<64, 256, 0, stream>>>(partial, b4, ctl, d_out, NBF);
}